// Round 3
// baseline (125.311 us; speedup 1.0000x reference)
//
#include <hip/hip_runtime.h>
#include <math.h>

// RansacRouting: B=32, I=1152, O=10, D=16, H=10, S=922
// v[b,o,:] == Mu[b,o,:,h*], h* = argmin_h loss.
// 3-kernel pipeline:
//   K1 (per b,o): tot-scan + masks + complement lists + Mu  -> ws
//   K2 (per b,o,h): loss scan over all I, packed atomicMin argmin
//   K3: copy Mu[h*] -> out

#define B_    32
#define I_    1152
#define O_    10
#define D_    16
#define H_    10
#define S_    922
#define COMP  230     // I_ - S_
#define MASKW 36      // 1152/32

// ---- wave64 sum via DPP (VALU pipe) -- result valid in lane 63 ----
template <int CTRL, int ROWM>
static __device__ __forceinline__ float dpp_f(float v) {
    return __int_as_float(__builtin_amdgcn_update_dpp(
        0, __float_as_int(v), CTRL, ROWM, 0xf, true));
}
static __device__ __forceinline__ float wave_sum_f32(float v) {
    v += dpp_f<0x111, 0xf>(v);   // row_shr:1
    v += dpp_f<0x112, 0xf>(v);   // row_shr:2
    v += dpp_f<0x114, 0xf>(v);   // row_shr:4
    v += dpp_f<0x118, 0xf>(v);   // row_shr:8
    v += dpp_f<0x142, 0xa>(v);   // row_bcast15
    v += dpp_f<0x143, 0xc>(v);   // row_bcast31
    return v;
}
template <int CTRL, int ROWM>
static __device__ __forceinline__ double dpp_d(double v) {
    long long x = __double_as_longlong(v);
    int lo = (int)(unsigned)(x & 0xffffffffLL);
    int hi = (int)(x >> 32);
    lo = __builtin_amdgcn_update_dpp(0, lo, CTRL, ROWM, 0xf, true);
    hi = __builtin_amdgcn_update_dpp(0, hi, CTRL, ROWM, 0xf, true);
    return __longlong_as_double((long long)(unsigned)lo | ((long long)hi << 32));
}
static __device__ __forceinline__ double wave_sum_f64(double v) {
    v += dpp_d<0x111, 0xf>(v);
    v += dpp_d<0x112, 0xf>(v);
    v += dpp_d<0x114, 0xf>(v);
    v += dpp_d<0x118, 0xf>(v);
    v += dpp_d<0x142, 0xa>(v);
    v += dpp_d<0x143, 0xc>(v);
    return v;
}

// =================== K1: tot + masks + clist + Mu ===================
__global__ __launch_bounds__(640, 1) void k1_mask_mu(
    const float* __restrict__ up,      // [B,I,O,D]
    const int*   __restrict__ sidx,    // [B,S,O,H]
    float*       __restrict__ muw,     // [B,O,H,D] ws
    unsigned long long* __restrict__ winner)  // [B*O] ws
{
    __shared__ unsigned       mask[H_][MASKW];
    __shared__ unsigned short clist[H_][COMP];
    __shared__ int            ccount[H_];
    __shared__ float          totred[10][17];
    __shared__ float          tot[17];

    // XCD swizzle: 10 o-blocks of one b share an XCD
    const int blk = blockIdx.x;
    const int xcd = blk & 7, g = blk >> 3;          // g in [0,40)
    const int b   = xcd + 8 * (g / O_);
    const int o   = g - (g / O_) * O_;
    const int bo  = b * O_ + o;

    const int tid  = threadIdx.x;
    const int lane = tid & 63;
    const int wv   = tid >> 6;                      // 10 waves

    for (int j = tid; j < H_ * MASKW; j += 640) ((unsigned*)mask)[j] = 0u;
    if (tid < H_) ccount[tid] = 0;
    if (tid == 0) winner[bo] = ~0ULL;
    __syncthreads();

    // --- A: tot[0..15] = sum vn*u_d ; tot[16] = sum vn ---
    const float* ub = up + ((size_t)b * I_ * O_ + o) * D_;
    float acc[17];
    #pragma unroll
    for (int d = 0; d < 17; ++d) acc[d] = 0.f;
    for (int i = tid; i < I_; i += 640) {
        const float4* p = (const float4*)(ub + (size_t)i * (O_ * D_));
        float4 q0 = p[0], q1 = p[1], q2 = p[2], q3 = p[3];
        float s = q0.x*q0.x + q0.y*q0.y + q0.z*q0.z + q0.w*q0.w
                + q1.x*q1.x + q1.y*q1.y + q1.z*q1.z + q1.w*q1.w
                + q2.x*q2.x + q2.y*q2.y + q2.z*q2.z + q2.w*q2.w
                + q3.x*q3.x + q3.y*q3.y + q3.z*q3.z + q3.w*q3.w;
        float vn = sqrtf(s);
        acc[ 0] = fmaf(vn, q0.x, acc[ 0]); acc[ 1] = fmaf(vn, q0.y, acc[ 1]);
        acc[ 2] = fmaf(vn, q0.z, acc[ 2]); acc[ 3] = fmaf(vn, q0.w, acc[ 3]);
        acc[ 4] = fmaf(vn, q1.x, acc[ 4]); acc[ 5] = fmaf(vn, q1.y, acc[ 5]);
        acc[ 6] = fmaf(vn, q1.z, acc[ 6]); acc[ 7] = fmaf(vn, q1.w, acc[ 7]);
        acc[ 8] = fmaf(vn, q2.x, acc[ 8]); acc[ 9] = fmaf(vn, q2.y, acc[ 9]);
        acc[10] = fmaf(vn, q2.z, acc[10]); acc[11] = fmaf(vn, q2.w, acc[11]);
        acc[12] = fmaf(vn, q3.x, acc[12]); acc[13] = fmaf(vn, q3.y, acc[13]);
        acc[14] = fmaf(vn, q3.z, acc[14]); acc[15] = fmaf(vn, q3.w, acc[15]);
        acc[16] += vn;
    }

    // --- B: scatter hypothesis membership bits ---
    const int* sb = sidx + (size_t)b * (S_ * O_ * H_) + o * H_;
    for (int j = tid; j < S_ * H_; j += 640) {
        int s = j / H_;
        int h = j - s * H_;
        int idx = sb[s * (O_ * H_) + h];
        atomicOr(&mask[h][idx >> 5], 1u << (idx & 31));
    }

    #pragma unroll
    for (int d = 0; d < 17; ++d) acc[d] = wave_sum_f32(acc[d]);
    if (lane == 63) {
        #pragma unroll
        for (int d = 0; d < 17; ++d) totred[wv][d] = acc[d];
    }
    __syncthreads();   // masks + totred complete

    if (tid < 17) {
        float t = 0.f;
        #pragma unroll
        for (int w = 0; w < 10; ++w) t += totred[w][tid];
        tot[tid] = t;
    }

    // --- C: complement index lists (exactly 230 per h) ---
    if (lane < MASKW) {
        const int h = wv;
        unsigned m = ~mask[h][lane];
        int cnt = __popc(m);
        int base = atomicAdd(&ccount[h], cnt);
        while (m) {
            int bit = __ffs(m) - 1;
            m &= m - 1u;
            clist[h][base++] = (unsigned short)((lane << 5) + bit);
        }
    }
    __syncthreads();   // clist + tot ready

    // --- D: Mu_h = (tot - sum_comp vn*u) / (totn - sum_comp vn), gather from L2 ---
    {
        const int h = wv;
        float na[17];
        #pragma unroll
        for (int d = 0; d < 17; ++d) na[d] = 0.f;
        for (int k = lane; k < COMP; k += 64) {
            int i = clist[h][k];
            const float4* p = (const float4*)(ub + (size_t)i * (O_ * D_));
            float4 q0 = p[0], q1 = p[1], q2 = p[2], q3 = p[3];
            float s = q0.x*q0.x + q0.y*q0.y + q0.z*q0.z + q0.w*q0.w
                    + q1.x*q1.x + q1.y*q1.y + q1.z*q1.z + q1.w*q1.w
                    + q2.x*q2.x + q2.y*q2.y + q2.z*q2.z + q2.w*q2.w
                    + q3.x*q3.x + q3.y*q3.y + q3.z*q3.z + q3.w*q3.w;
            float vn = sqrtf(s);
            na[ 0] = fmaf(vn, q0.x, na[ 0]); na[ 1] = fmaf(vn, q0.y, na[ 1]);
            na[ 2] = fmaf(vn, q0.z, na[ 2]); na[ 3] = fmaf(vn, q0.w, na[ 3]);
            na[ 4] = fmaf(vn, q1.x, na[ 4]); na[ 5] = fmaf(vn, q1.y, na[ 5]);
            na[ 6] = fmaf(vn, q1.z, na[ 6]); na[ 7] = fmaf(vn, q1.w, na[ 7]);
            na[ 8] = fmaf(vn, q2.x, na[ 8]); na[ 9] = fmaf(vn, q2.y, na[ 9]);
            na[10] = fmaf(vn, q2.z, na[10]); na[11] = fmaf(vn, q2.w, na[11]);
            na[12] = fmaf(vn, q3.x, na[12]); na[13] = fmaf(vn, q3.y, na[13]);
            na[14] = fmaf(vn, q3.z, na[14]); na[15] = fmaf(vn, q3.w, na[15]);
            na[16] += vn;
        }
        #pragma unroll
        for (int d = 0; d < 17; ++d) na[d] = wave_sum_f32(na[d]);
        if (lane == 63) {
            float rd = 1.f / (tot[16] - na[16]);
            float* mo = muw + ((size_t)bo * H_ + h) * D_;
            #pragma unroll
            for (int d = 0; d < D_; ++d) mo[d] = (tot[d] - na[d]) * rd;
        }
    }
}

// =================== K2: per-(b,o,h) loss + packed argmin ===================
__global__ __launch_bounds__(256, 4) void k2_loss(
    const float* __restrict__ up,
    const float* __restrict__ muw,
    unsigned long long* __restrict__ winner)
{
    __shared__ double lpart[4];

    // swizzle: all blocks of one b stay on one XCD; u[b] (737 KB) fits its 4 MB L2
    const int g   = blockIdx.x;
    const int xcd = g & 7;
    const int r   = g >> 3;             // [0,400)
    const int bhi = r / 100;
    const int rem = r - 100 * bhi;      // [0,100)
    const int o   = rem / 10;
    const int h   = rem - 10 * o;
    const int b   = bhi * 8 + xcd;
    const int bo  = b * O_ + o;

    const int tid  = threadIdx.x;
    const int lane = tid & 63;
    const int wv   = tid >> 6;

    const float* mo = muw + ((size_t)bo * H_ + h) * D_;
    float mu[D_];
    #pragma unroll
    for (int d = 0; d < D_; ++d) mu[d] = mo[d];
    float musq = 0.f;
    #pragma unroll
    for (int d = 0; d < D_; ++d) musq = fmaf(mu[d], mu[d], musq);

    const float* ub = up + ((size_t)b * I_ * O_ + o) * D_;
    double lacc = 0.0;
    for (int i = tid; i < I_; i += 256) {
        const float4* p = (const float4*)(ub + (size_t)i * (O_ * D_));
        float4 q0 = p[0], q1 = p[1], q2 = p[2], q3 = p[3];
        float uq[D_] = {q0.x,q0.y,q0.z,q0.w, q1.x,q1.y,q1.z,q1.w,
                        q2.x,q2.y,q2.z,q2.w, q3.x,q3.y,q3.z,q3.w};
        float usq = 0.f, dot = 0.f;
        #pragma unroll
        for (int d = 0; d < D_; ++d) {
            usq = fmaf(uq[d], uq[d], usq);
            dot = fmaf(uq[d], mu[d], dot);
        }
        float d2 = fmaf(-2.f, dot, usq + musq);
        lacc += (double)sqrtf(fmaxf(d2, 0.f));
    }
    lacc = wave_sum_f64(lacc);
    if (lane == 63) lpart[wv] = lacc;
    __syncthreads();
    if (tid == 0) {
        double L = lpart[0] + lpart[1] + lpart[2] + lpart[3];
        // positive double -> monotone bit pattern; low 4 bits carry h.
        // On ties the smaller h wins (== np.argmin first-min tie-break).
        unsigned long long pk =
            (((unsigned long long)__double_as_longlong(L)) & ~0xFULL) | (unsigned)h;
        atomicMin(&winner[bo], pk);
    }
}

// =================== K3: winner lookup -> out ===================
__global__ __launch_bounds__(256, 4) void k3_out(
    const float* __restrict__ muw,
    const unsigned long long* __restrict__ winner,
    float* __restrict__ out)
{
    int g = blockIdx.x * 256 + threadIdx.x;
    if (g < B_ * O_ * D_) {
        int bo = g >> 4;
        int d  = g & 15;
        int h  = (int)(winner[bo] & 0xF);
        out[g] = muw[((size_t)bo * H_ + h) * D_ + d];
    }
}

extern "C" void kernel_launch(void* const* d_in, const int* in_sizes, int n_in,
                              void* d_out, int out_size, void* d_ws, size_t ws_size,
                              hipStream_t stream) {
    const float* up   = (const float*)d_in[0];
    const int*   sidx = (const int*)d_in[1];
    float*       out  = (float*)d_out;

    float* muw = (float*)d_ws;                                    // 3200*16 f32 = 204800 B
    unsigned long long* winner = (unsigned long long*)((char*)d_ws + 204800);  // 320*8 B

    k1_mask_mu<<<B_ * O_,      640, 0, stream>>>(up, sidx, muw, winner);
    k2_loss   <<<B_ * O_ * H_, 256, 0, stream>>>(up, muw, winner);
    k3_out    <<<(B_ * O_ * D_ + 255) / 256, 256, 0, stream>>>(muw, winner, out);
}